// Round 4
// baseline (104.004 us; speedup 1.0000x reference)
//
#include <hip/hip_runtime.h>
#include <hip/hip_bf16.h>

// Problem constants
constexpr int   kN  = 4096;
constexpr int   kD  = 256;
constexpr float kNU = 3.0f;
constexpr int   kNB = kN / 128;                // 32 block-rows/cols
constexpr int   kNPairs = kNB * (kNB + 1) / 2; // 528 upper-tri block pairs

using bf16x8 = __attribute__((ext_vector_type(8))) __bf16;
using bf16x4 = __attribute__((ext_vector_type(4))) __bf16;
using f32x4  = __attribute__((ext_vector_type(4))) float;
using f16x4  = __attribute__((ext_vector_type(4))) _Float16;

// ---------------------------------------------------------------------------
// K1: per-row norms + coeff + fp32->bf16; zero ghist/accd/counter
// ---------------------------------------------------------------------------
__global__ __launch_bounds__(256) void prep_kernel(
    const float* __restrict__ z, __bf16* __restrict__ zh,
    float* __restrict__ norms, float* __restrict__ coef,
    unsigned int* __restrict__ ghist, double* __restrict__ accd,
    unsigned int* __restrict__ counter) {
  int tid = threadIdx.x;
  if (blockIdx.x < 16) ghist[blockIdx.x * 256 + tid] = 0u;
  if (blockIdx.x == 16 && tid == 0) { accd[0] = 0.0; counter[0] = 0u; }

  int w = tid >> 6, lane = tid & 63;
  int row = blockIdx.x * 4 + w;
  const float4 v = *(const float4*)(z + (size_t)row * kD + lane * 4);
  bf16x4 h;
  h[0] = (__bf16)v.x; h[1] = (__bf16)v.y; h[2] = (__bf16)v.z; h[3] = (__bf16)v.w;
  *(bf16x4*)(zh + (size_t)row * kD + lane * 4) = h;

  float sq = v.x * v.x + v.y * v.y + v.z * v.z + v.w * v.w;
  for (int off = 32; off > 0; off >>= 1) sq += __shfl_down(sq, off, 64);
  if (lane == 0) {
    norms[row] = sq;
    coef[row] = -(kNU + (float)kD) / (kNU + sq);   // sigma = 1
  }
}

// ---------------------------------------------------------------------------
// Gram tile main loop (128x128, BK=64, global_load_lds, XOR-swizzled chunks)
// ---------------------------------------------------------------------------
__device__ __forceinline__ void gram_tile(
    const __bf16* __restrict__ zh, int bRow, int bCol, int tid,
    __bf16* ldsA, __bf16* ldsB, f32x4 acc[4][4]) {
  int lane = tid & 63, w = tid >> 6;
  int quad = lane >> 4, l15 = lane & 15;
  int waveM = (w >> 1) * 64, waveN = (w & 1) * 64;

  for (int kc = 0; kc < 4; kc++) {
    if (kc) __syncthreads();
#pragma unroll
    for (int s = 0; s < 4; s++) {
      int slot = (w * 4 + s) * 64 + lane;
      int row = slot >> 3;
      int cp = slot & 7;
      int c = cp ^ (row & 7);
      const __bf16* gA = zh + (size_t)(bRow + row) * kD + kc * 64 + c * 8;
      const __bf16* gB = zh + (size_t)(bCol + row) * kD + kc * 64 + c * 8;
      __builtin_amdgcn_global_load_lds(
          (const __attribute__((address_space(1))) void*)gA,
          (__attribute__((address_space(3))) void*)(ldsA + (size_t)(w * 4 + s) * 512),
          16, 0, 0);
      __builtin_amdgcn_global_load_lds(
          (const __attribute__((address_space(1))) void*)gB,
          (__attribute__((address_space(3))) void*)(ldsB + (size_t)(w * 4 + s) * 512),
          16, 0, 0);
    }
    __syncthreads();
#pragma unroll
    for (int ks = 0; ks < 2; ks++) {
      bf16x8 aF[4], bF[4];
#pragma unroll
      for (int mi = 0; mi < 4; mi++) {
        int row = waveM + mi * 16 + l15;
        int cp = ((ks << 2) | quad) ^ (row & 7);
        aF[mi] = *(const bf16x8*)(ldsA + row * 64 + cp * 8);
      }
#pragma unroll
      for (int ni = 0; ni < 4; ni++) {
        int row = waveN + ni * 16 + l15;
        int cp = ((ks << 2) | quad) ^ (row & 7);
        bF[ni] = *(const bf16x8*)(ldsB + row * 64 + cp * 8);
      }
#pragma unroll
      for (int mi = 0; mi < 4; mi++)
#pragma unroll
        for (int ni = 0; ni < 4; ni++)
          acc[mi][ni] = __builtin_amdgcn_mfma_f32_16x16x32_bf16(
              aF[mi], bF[ni], acc[mi][ni], 0, 0, 0);
    }
  }
}

__device__ __forceinline__ void tri_decode(int b, int& by, int& bx) {
  int t = b; by = 0;
  while (t >= kNB - by) { t -= kNB - by; by++; }
  bx = by + t;
}

// ---------------------------------------------------------------------------
// K2: gram -> dist_sq; store dist tile (fp16) + histogram (4096 bins, w=0.25)
// ---------------------------------------------------------------------------
__global__ __launch_bounds__(256) void gemm_hist(
    const __bf16* __restrict__ zh, const float* __restrict__ norms,
    unsigned int* __restrict__ ghist, _Float16* __restrict__ dist_out) {
  __shared__ __bf16 ldsA[128 * 64], ldsB[128 * 64];
  __shared__ unsigned int hist[4096];
  __shared__ float nR[128], nC[128];
  int tid = threadIdx.x;
  for (int i = tid; i < 4096; i += 256) hist[i] = 0;

  int by, bx; tri_decode(blockIdx.x, by, bx);
  int bRow = by * 128, bCol = bx * 128;
  if (tid < 128) nR[tid] = norms[bRow + tid];
  else           nC[tid - 128] = norms[bCol + tid - 128];

  int lane = tid & 63, w = tid >> 6;
  int quad = lane >> 4, l15 = lane & 15;
  int waveM = (w >> 1) * 64, waveN = (w & 1) * 64;

  f32x4 acc[4][4] = {};
  gram_tile(zh, bRow, bCol, tid, ldsA, ldsB, acc);

  _Float16* dtile = dist_out + (size_t)blockIdx.x * 16384;
  unsigned int wgt = (by == bx) ? 1u : 2u;
#pragma unroll
  for (int mi = 0; mi < 4; mi++) {
    int rl0 = waveM + mi * 16 + quad * 4;
#pragma unroll
    for (int r = 0; r < 4; r++) {
      int rl = rl0 + r;
      float ni_ = nR[rl];
#pragma unroll
      for (int nj = 0; nj < 4; nj++) {
        int cl = waveN + nj * 16 + l15;
        float g = acc[mi][nj][r];
        float dist = fmaxf(ni_ + nC[cl] - 2.0f * g, 0.0f);
        dtile[rl * 128 + cl] = (_Float16)dist;
        int bin = (int)(dist * 4.0f);
        bin = bin > 4095 ? 4095 : bin;
        atomicAdd(&hist[bin], wgt);
      }
    }
  }
  __syncthreads();
  for (int i = tid; i < 4096; i += 256) {
    unsigned int h = hist[i];
    if (h) atomicAdd(&ghist[i], h);
  }
}

// ---------------------------------------------------------------------------
// K3: fused median + k_stein loss + last-block finalize
// ---------------------------------------------------------------------------
__global__ __launch_bounds__(256) void loss_fused(
    const _Float16* __restrict__ dist_in, const unsigned int* __restrict__ ghist,
    const float* __restrict__ norms, const float* __restrict__ coef,
    double* __restrict__ accd, unsigned int* __restrict__ counter,
    float* __restrict__ out) {
  __shared__ float nR[128], nC[128], cR[128], cC[128];
  __shared__ float sAlpha;
  __shared__ double dpart[4];
  int tid = threadIdx.x;
  int by, bx; tri_decode(blockIdx.x, by, bx);
  int bRow = by * 128, bCol = bx * 128;
  if (tid < 128) { nR[tid] = norms[bRow + tid]; cR[tid] = coef[bRow + tid]; }
  else { int u = tid - 128; nC[u] = norms[bCol + u]; cC[u] = coef[bCol + u]; }

  // wave 0: two-level parallel median scan over 4096-bin histogram
  if (tid < 64) {
    int lane = tid;
    const uint4* g4 = (const uint4*)ghist;
    unsigned own = 0;
#pragma unroll
    for (int u = 0; u < 16; u++) {
      uint4 v = g4[lane * 16 + u];
      own += v.x + v.y + v.z + v.w;
    }
    unsigned incl = own;
#pragma unroll
    for (int off = 1; off < 64; off <<= 1) {
      unsigned t = __shfl_up(incl, off, 64);
      if (lane >= off) incl += t;
    }
    const unsigned target = ((unsigned)kN * (unsigned)kN - 1u) / 2u + 1u;
    unsigned excl = incl - own;
    unsigned long long bal = __ballot(incl >= target && excl < target);
    int chunk = __ffsll((long long)bal) - 1;
    unsigned exclChunk = __shfl(excl, chunk, 64);
    // fine level: 64 bins of the owning chunk
    unsigned h = ghist[chunk * 64 + lane];
    unsigned fincl = h;
#pragma unroll
    for (int off = 1; off < 64; off <<= 1) {
      unsigned t = __shfl_up(fincl, off, 64);
      if (lane >= off) fincl += t;
    }
    unsigned long long cum = (unsigned long long)exclChunk + (fincl - h);
    if (cum < target && cum + h >= target) {
      int b = chunk * 64 + lane;
      float frac = (float)(target - cum) / (float)h;
      float med = ((float)b + frac) * 0.25f;
      sAlpha = 1.0f / (med + 1e-6f);
    }
  }
  __syncthreads();

  const float alpha = sAlpha;
  const bool diag = (by == bx);
  const float wf = diag ? 1.0f : 2.0f;
  const f16x4* base4 = (const f16x4*)(dist_in + (size_t)blockIdx.x * 16384);

  float part = 0.0f;
#pragma unroll
  for (int i = 0; i < 16; i++) {
    int o4 = tid + i * 256;          // f16x4 index in tile (4096 total)
    int row = o4 >> 5;               // 32 f16x4 per 128-wide row
    int col0 = (o4 & 31) * 4;
    f16x4 dv = base4[o4];
    float ni_ = nR[row], ci = cR[row];
#pragma unroll
    for (int e = 0; e < 4; e++) {
      int col = col0 + e;
      float dist = (float)dv[e];
      float njv = nC[col], cj = cC[col];
      float g = 0.5f * (ni_ + njv - dist);
      float base = fmaf(alpha, dist, 1.0f);
      float rq  = rsqrtf(base);      // K = base^-0.5
      float rq2 = rq * rq;
      float gc  = -alpha * rq * rq2; // grad_coeff
      float ta  = ci * cj * g * rq;
      float tb  = -gc * ci * (ni_ - g);
      float tc  =  gc * cj * (g - njv);
      float lap =  gc * ((float)kD - 3.0f * alpha * dist * rq2);
      float v = ta + tb + tc + lap;
      if (!(diag && row == col)) part += wf * v;
    }
  }

  int lane = tid & 63, w = tid >> 6;
  double d = (double)part;
  for (int off = 32; off > 0; off >>= 1) d += __shfl_down(d, off, 64);
  if (lane == 0) dpart[w] = d;
  __syncthreads();
  if (tid == 0) {
    atomicAdd(accd, dpart[0] + dpart[1] + dpart[2] + dpart[3]);
    __threadfence();
    unsigned old = atomicAdd(counter, 1u);
    if (old == (unsigned)(kNPairs - 1)) {
      double tot = atomicAdd(accd, 0.0);  // device-coherent readback
      out[0] = (float)(tot / ((double)kN * (double)(kN - 1)));
    }
  }
}

// ---------------------------------------------------------------------------
extern "C" void kernel_launch(void* const* d_in, const int* in_sizes, int n_in,
                              void* d_out, int out_size, void* d_ws, size_t ws_size,
                              hipStream_t stream) {
  const float* z = (const float*)d_in[0];
  float* out = (float*)d_out;

  char* ws = (char*)d_ws;
  __bf16* zh = (__bf16*)ws;                                   // 2 MB
  float* norms = (float*)(ws + (size_t)kN * kD * 2);
  float* coef  = norms + kN;
  unsigned int* ghist = (unsigned int*)(coef + kN);
  double* accd = (double*)(ghist + 4096);                     // 8-aligned
  unsigned int* counter = (unsigned int*)(accd + 1);
  _Float16* dist = (_Float16*)(ws + (4 << 20));               // 17.3 MB @ +4MB

  prep_kernel<<<kN / 4, 256, 0, stream>>>(z, zh, norms, coef, ghist, accd, counter);
  gemm_hist<<<kNPairs, 256, 0, stream>>>(zh, norms, ghist, dist);
  loss_fused<<<kNPairs, 256, 0, stream>>>(dist, ghist, norms, coef, accd, counter, out);
}